// Round 7
// baseline (299.886 us; speedup 1.0000x reference)
//
#include <hip/hip_runtime.h>
#include <hip/hip_bf16.h>
#include <math.h>

typedef __bf16 bf16_t;
typedef bf16_t bf16x8 __attribute__((ext_vector_type(8)));
typedef float f32x4 __attribute__((ext_vector_type(4)));

#define BB 4
#define SS 2048
#define HH 16
#define DMODEL 1024
#define DHEAD 64

// Q is pre-scaled by 1/sqrt(64) * log2(e) so attention probs are exp2(q.k)
#define QSCALE 0.18033688011112042f

__device__ inline unsigned short f2bf(float f) {
    union { __hip_bfloat16 h; unsigned short u; } cvt;
    cvt.h = __float2bfloat16(f);
    return cvt.u;
}

// async global->LDS, 16B per lane. LDS dest = wave-uniform base + lane*16.
__device__ __forceinline__ void gll16(const unsigned short* g, unsigned short* l) {
    __builtin_amdgcn_global_load_lds(
        (const __attribute__((address_space(1))) unsigned int*)(g),
        (__attribute__((address_space(3))) unsigned int*)(l), 16, 0, 0);
}

// ---------------- fused pack kernel ----------------

__global__ void pack_all(const float* __restrict__ x,
                         const float* __restrict__ wq, const float* __restrict__ wk,
                         const float* __restrict__ wv, const float* __restrict__ wo,
                         unsigned short* __restrict__ xb, unsigned short* __restrict__ wqkv,
                         unsigned short* __restrict__ woT) {
    const int bid = blockIdx.x;
    if (bid < 8192) {
        int i = bid * 256 + threadIdx.x;
        const float4 v = ((const float4*)x)[i];
        unsigned short o[4] = { f2bf(v.x), f2bf(v.y), f2bf(v.z), f2bf(v.w) };
        *(uint2*)(xb + 4 * (size_t)i) = *(uint2*)o;
    } else if (bid < 8192 + 12288) {
        int idx = (bid - 8192) * 256 + threadIdx.x;
        int k  = idx & 1023;
        int n  = idx >> 10;
        int mat = n >> 10;
        int n1 = n & 1023;
        int h = n1 >> 6, d = n1 & 63;
        const float* wsrc = (mat == 0) ? wq : (mat == 1) ? wk : wv;
        wqkv[idx] = f2bf(wsrc[(h << 16) + (k << 6) + d]);
    } else {
        int idx = (bid - 20480) * 256 + threadIdx.x;
        int k = idx & 1023, n = idx >> 10;
        woT[idx] = f2bf(wo[(k << 10) + n]);
    }
}

// ---------------- GEMM 1 (r1-proven 2-phase 128x128, ~3 blocks/CU overlap) ----------------

__global__ __launch_bounds__(256) void gemm_qkv(
    const unsigned short* __restrict__ xb,    // [8192][1024]
    const unsigned short* __restrict__ wT,    // [3072][1024]
    const float* __restrict__ bq, const float* __restrict__ bk, const float* __restrict__ bv,
    unsigned short* __restrict__ qws, unsigned short* __restrict__ kws,
    unsigned short* __restrict__ vtw)         // [64][64][2048]
{
    __shared__ __align__(16) unsigned short lA[128 * 32];   // lane-linear, no pad (gll constraint)
    __shared__ __align__(16) unsigned short lB[128 * 32];
    const int t = threadIdx.x;
    const int lane = t & 63;
    const int w = t >> 6;
    const int quad = lane >> 4;
    const int l15 = lane & 15;
    const int n0 = blockIdx.x * 128;
    const int m0 = blockIdx.y * 128;
    const int wm = (w >> 1) * 64;
    const int wn = (w & 1) * 64;
    const int mat = n0 >> 10;                 // uniform per block (1024 % 128 == 0)

    f32x4 acc[4][4] = {};

    const int srow = w * 16 + (lane >> 2);
    const int scol = (lane & 3) * 8;
    const unsigned short* Ag0 = xb + (size_t)(m0 + srow) * 1024 + scol;
    const unsigned short* Ag1 = Ag0 + (size_t)64 * 1024;
    const unsigned short* Bg0 = wT + (size_t)(n0 + srow) * 1024 + scol;
    const unsigned short* Bg1 = Bg0 + (size_t)64 * 1024;
    unsigned short* lA0 = lA + (w * 16) * 32;
    unsigned short* lA1 = lA + (64 + w * 16) * 32;
    unsigned short* lB0 = lB + (w * 16) * 32;
    unsigned short* lB1 = lB + (64 + w * 16) * 32;

    if (mat != 2) {
        // swapped operands: D[m=weight n][n=x row s]
        for (int kt = 0; kt < 1024; kt += 32) {
            __syncthreads();
            gll16(Ag0 + kt, lA0);
            gll16(Ag1 + kt, lA1);
            gll16(Bg0 + kt, lB0);
            gll16(Bg1 + kt, lB1);
            __syncthreads();
            bf16x8 af[4], bfr[4];
#pragma unroll
            for (int i = 0; i < 4; i++) {
                af[i]  = *(const bf16x8*)(lA + (wm + i * 16 + l15) * 32 + quad * 8);
                bfr[i] = *(const bf16x8*)(lB + (wn + i * 16 + l15) * 32 + quad * 8);
            }
#pragma unroll
            for (int i = 0; i < 4; i++)
#pragma unroll
                for (int j = 0; j < 4; j++)
                    acc[i][j] = __builtin_amdgcn_mfma_f32_16x16x32_bf16(bfr[j], af[i], acc[i][j], 0, 0, 0);
        }
        // epilogue: lane holds 4 consecutive d at fixed s -> uint2 stores
        const int b = m0 >> 11;
        const float* bias_p = (mat == 0) ? bq : bk;
        const float scale = (mat == 0) ? QSCALE : 1.0f;   // fold softmax scale+log2e into Q
        unsigned short* dst = (mat == 0) ? qws : kws;
#pragma unroll
        for (int j = 0; j < 4; j++) {
            const int noff = wn + j * 16 + quad * 4;          // 0..124
            const int h = noff >> 6;
            const int hglob = ((n0 & 1023) >> 6) + h;
            const int dbase = noff & 63;
            const float4 bv4 = *(const float4*)(bias_p + hglob * 64 + dbase);
            const float bias_r[4] = { bv4.x, bv4.y, bv4.z, bv4.w };
#pragma unroll
            for (int i = 0; i < 4; i++) {
                const int s = (m0 & 2047) + wm + i * 16 + l15;
                unsigned short pk[4];
#pragma unroll
                for (int r = 0; r < 4; r++) pk[r] = f2bf((acc[i][j][r] + bias_r[r]) * scale);
                *(uint2*)(dst + (size_t)((b * 16 + hglob) * 2048 + s) * 64 + dbase) = *(uint2*)pk;
            }
        }
    } else {
        // normal order: D[m=x row s][n=weight] -> 4 consecutive s at fixed d -> uint2 into V^T
        for (int kt = 0; kt < 1024; kt += 32) {
            __syncthreads();
            gll16(Ag0 + kt, lA0);
            gll16(Ag1 + kt, lA1);
            gll16(Bg0 + kt, lB0);
            gll16(Bg1 + kt, lB1);
            __syncthreads();
            bf16x8 af[4], bfr[4];
#pragma unroll
            for (int i = 0; i < 4; i++) {
                af[i]  = *(const bf16x8*)(lA + (wm + i * 16 + l15) * 32 + quad * 8);
                bfr[i] = *(const bf16x8*)(lB + (wn + i * 16 + l15) * 32 + quad * 8);
            }
#pragma unroll
            for (int i = 0; i < 4; i++)
#pragma unroll
                for (int j = 0; j < 4; j++)
                    acc[i][j] = __builtin_amdgcn_mfma_f32_16x16x32_bf16(af[i], bfr[j], acc[i][j], 0, 0, 0);
        }
        const int b = m0 >> 11;
#pragma unroll
        for (int j = 0; j < 4; j++) {
            const int n1 = (n0 & 1023) + wn + j * 16 + l15;
            const int h = n1 >> 6, d = n1 & 63;
            const float bias = bv[h * 64 + d];
#pragma unroll
            for (int i = 0; i < 4; i++) {
                const int s0 = (m0 & 2047) + wm + i * 16 + quad * 4;
                unsigned short pk[4];
#pragma unroll
                for (int r = 0; r < 4; r++) pk[r] = f2bf(acc[i][j][r] + bias);
                *(uint2*)(vtw + ((size_t)(b * 16 + h) * 64 + d) * 2048 + s0) = *(uint2*)pk;
            }
        }
    }
}

// ---------------- GEMM 2 (r1-proven 2-phase 128x128): out = z @ WoT^T + bO ----------------

__global__ __launch_bounds__(256) void gemm_out(
    const unsigned short* __restrict__ zb,    // [8192][1024]
    const unsigned short* __restrict__ wT,    // [1024][1024]
    const float* __restrict__ bo,
    float* __restrict__ out)
{
    __shared__ __align__(16) unsigned short lA[128 * 32];
    __shared__ __align__(16) unsigned short lB[128 * 32];
    const int t = threadIdx.x;
    const int lane = t & 63;
    const int w = t >> 6;
    const int quad = lane >> 4;
    const int l15 = lane & 15;
    const int n0 = blockIdx.x * 128;
    const int m0 = blockIdx.y * 128;
    const int wm = (w >> 1) * 64;
    const int wn = (w & 1) * 64;

    f32x4 acc[4][4] = {};

    const int srow = w * 16 + (lane >> 2);
    const int scol = (lane & 3) * 8;
    const unsigned short* Ag0 = zb + (size_t)(m0 + srow) * 1024 + scol;
    const unsigned short* Ag1 = Ag0 + (size_t)64 * 1024;
    const unsigned short* Bg0 = wT + (size_t)(n0 + srow) * 1024 + scol;
    const unsigned short* Bg1 = Bg0 + (size_t)64 * 1024;
    unsigned short* lA0 = lA + (w * 16) * 32;
    unsigned short* lA1 = lA + (64 + w * 16) * 32;
    unsigned short* lB0 = lB + (w * 16) * 32;
    unsigned short* lB1 = lB + (64 + w * 16) * 32;

    for (int kt = 0; kt < 1024; kt += 32) {
        __syncthreads();
        gll16(Ag0 + kt, lA0);
        gll16(Ag1 + kt, lA1);
        gll16(Bg0 + kt, lB0);
        gll16(Bg1 + kt, lB1);
        __syncthreads();
        bf16x8 af[4], bfr[4];
#pragma unroll
        for (int i = 0; i < 4; i++) {
            af[i]  = *(const bf16x8*)(lA + (wm + i * 16 + l15) * 32 + quad * 8);
            bfr[i] = *(const bf16x8*)(lB + (wn + i * 16 + l15) * 32 + quad * 8);
        }
#pragma unroll
        for (int i = 0; i < 4; i++)
#pragma unroll
            for (int j = 0; j < 4; j++)
                acc[i][j] = __builtin_amdgcn_mfma_f32_16x16x32_bf16(bfr[j], af[i], acc[i][j], 0, 0, 0);
    }

    // swapped D: lane holds 4 consecutive n at fixed s -> float4 stores
#pragma unroll
    for (int j = 0; j < 4; j++) {
        const int nbase = n0 + wn + j * 16 + quad * 4;
        const float4 bv4 = *(const float4*)(bo + nbase);
#pragma unroll
        for (int i = 0; i < 4; i++) {
            const int s = m0 + wm + i * 16 + l15;
            float4 v;
            v.x = acc[i][j][0] + bv4.x;
            v.y = acc[i][j][1] + bv4.y;
            v.z = acc[i][j][2] + bv4.z;
            v.w = acc[i][j][3] + bv4.w;
            *(float4*)(out + (size_t)s * 1024 + nbase) = v;
        }
    }
}

// ---------------- attention v7: K/V double-buffer, one barrier per chunk ----------------
// vs v6: K/V in 4 distinct 8KiB LDS objects with compile-time ping-pong (2x unrolled
// chunk loop, alternating register sets). Per chunk: write c+1 into nxt buffer
// (overlapped with compute on cur), issue c+2 global loads, ONE barrier at chunk
// end (the mid-chunk lgkmcnt(0) needed for the P round-trip also drains the K/V
// writes, so the barrier needs no extra wait). Prefetch depth 2 chunks (~700cy).

__device__ __forceinline__ f32x4 mfma_bf16(bf16x8 a, bf16x8 b, f32x4 c) {
    return __builtin_amdgcn_mfma_f32_16x16x32_bf16(a, b, c, 0, 0, 0);
}

__device__ __forceinline__ void attn_chunk(
    int c, int nch, int qbase, bool last,
    const unsigned short* Kg, const unsigned short* Vg,
    unsigned short* curK, unsigned short* curV,
    unsigned short* nxtK, unsigned short* nxtV,
    uint4& kin0, uint4& kin1, uint4& vin0, uint4& vin1,
    uint4& kout0, uint4& kout1, uint4& vout0, uint4& vout1,
    unsigned short* Pw,
    unsigned short* pws0, unsigned short* pws1, unsigned short* pws2, unsigned short* pws3,
    int sr, int sw0, int sw1, int l15, int quad, int gq0, int gq1,
    bf16x8 qf0, bf16x8 qf1, f32x4 (&o)[4], float& lsum)
{
    // stage chunk c+1 into the next buffer (cur is being read; nxt was freed by
    // the previous chunk-end barrier)
    if (c + 1 < nch) {
        *(uint4*)(nxtK + sr * 64 + sw0) = kin0;
        *(uint4*)(nxtK + sr * 64 + sw1) = kin1;
        *(uint4*)(nxtV + sr * 64 + sw0) = vin0;
        *(uint4*)(nxtV + sr * 64 + sw1) = vin1;
    }
    // issue chunk c+2 loads (consumed next chunk; ~2 chunks of latency cover)
    if (c + 2 < nch) {
        const unsigned short* kp = Kg + (size_t)(c + 2) * 64 * 64;
        const unsigned short* vp = Vg + (size_t)(c + 2) * 64;
        kout0 = *(const uint4*)(kp);
        kout1 = *(const uint4*)(kp + 32);
        vout0 = *(const uint4*)(vp);
        vout1 = *(const uint4*)(vp + 32);
    }

    // scores, swapped: A=K, B=Q -> D[row=key quad*4+r][col=q l15]
    f32x4 s[4];
    __builtin_amdgcn_s_setprio(1);
#pragma unroll
    for (int sub = 0; sub < 4; sub++) {
        const unsigned short* kr = curK + (sub * 16 + l15) * 64;
        bf16x8 kf0 = *(const bf16x8*)(kr + gq0);
        bf16x8 kf1 = *(const bf16x8*)(kr + gq1);
        f32x4 sv = {};
        sv = mfma_bf16(kf0, qf0, sv);
        sv = mfma_bf16(kf1, qf1, sv);
        s[sub] = sv;
    }
    __builtin_amdgcn_s_setprio(0);

    // fixed-max softmax: p = exp2(s); lane covers keys k0..k0+3 at q=qbase+l15
    const int kb = c * 64;
    if (last) {
        const int qg = qbase + l15;
#pragma unroll
        for (int sub = 0; sub < 4; sub++) {
            const int k0 = kb + sub * 16 + quad * 4;
            unsigned short pk[4];
#pragma unroll
            for (int r = 0; r < 4; r++) {
                float p = (k0 + r > qg) ? 0.f : exp2f(s[sub][r]);
                lsum += p;
                pk[r] = f2bf(p);
            }
            unsigned short* wp = (sub == 0) ? pws0 : (sub == 1) ? pws1 : (sub == 2) ? pws2 : pws3;
            *(uint2*)wp = *(uint2*)pk;
        }
    } else {
#pragma unroll
        for (int sub = 0; sub < 4; sub++) {
            unsigned short pk[4];
#pragma unroll
            for (int r = 0; r < 4; r++) {
                float p = exp2f(s[sub][r]);
                lsum += p;
                pk[r] = f2bf(p);
            }
            unsigned short* wp = (sub == 0) ? pws0 : (sub == 1) ? pws1 : (sub == 2) ? pws2 : pws3;
            *(uint2*)wp = *(uint2*)pk;
        }
    }
    // drain DS: covers P writes (needed for the cross-lane fragment read below)
    // AND the K/V nxt writes (needed before the chunk-end barrier)
    asm volatile("s_waitcnt lgkmcnt(0)" ::: "memory");
    bf16x8 pf0 = *(const bf16x8*)(Pw + l15 * 64 + gq0);
    bf16x8 pf1 = *(const bf16x8*)(Pw + l15 * 64 + gq1);
    __builtin_amdgcn_s_setprio(1);
#pragma unroll
    for (int dt = 0; dt < 4; dt++) {
        const unsigned short* vrp = curV + (dt * 16 + l15) * 64;
        bf16x8 vf0 = *(const bf16x8*)(vrp + gq0);
        bf16x8 vf1 = *(const bf16x8*)(vrp + gq1);
        o[dt] = mfma_bf16(vf0, pf0, o[dt]);
        o[dt] = mfma_bf16(vf1, pf1, o[dt]);
    }
    __builtin_amdgcn_s_setprio(0);
    __builtin_amdgcn_s_barrier();      // cur free for rewrite; nxt ready for read
    __builtin_amdgcn_sched_barrier(0);
}

__global__ __launch_bounds__(256) void attn3(
    const unsigned short* __restrict__ qws,
    const unsigned short* __restrict__ kws,
    const unsigned short* __restrict__ vtw,   // [bh][64][2048]
    unsigned short* __restrict__ zb)          // [8192][1024], col = h*64+d
{
    __shared__ __align__(16) unsigned short Ks0[64 * 64];
    __shared__ __align__(16) unsigned short Ks1[64 * 64];
    __shared__ __align__(16) unsigned short Vs0[64 * 64];   // [d][key]
    __shared__ __align__(16) unsigned short Vs1[64 * 64];
    __shared__ __align__(16) unsigned short Ps[4 * 16 * 64]; // per-wave [q=16][key=64]

    const int t = threadIdx.x;
    const int lane = t & 63;
    const int w = t >> 6;
    const int quad = lane >> 4;
    const int l15 = lane & 15;
    const int lo = l15 & 7;

    const int qt = 31 - (blockIdx.x >> 6);   // longest blocks dispatched first
    const int bh = blockIdx.x & 63;
    const int q0 = qt * 64;
    const int qbase = q0 + w * 16;
    const size_t base = (size_t)bh * SS * DHEAD;
    const unsigned short* Q = qws + base;
    const unsigned short* K = kws + base;
    const unsigned short* Vt = vtw + base;   // [64][2048]

    bf16x8 qf0 = *(const bf16x8*)(Q + (size_t)(qbase + l15) * 64 + quad * 8);
    bf16x8 qf1 = *(const bf16x8*)(Q + (size_t)(qbase + l15) * 64 + 32 + quad * 8);

    f32x4 o[4] = {};          // swapped PV: o[dt] rows = d (dt*16+quad*4+r), col = q (l15)
    float lsum = 0.f;         // row-sum for q = qbase + l15
    unsigned short* Pw = Ps + w * 16 * 64;

    // staging: thread t covers row sr, original col-granules (t&3) and (t&3)+4
    const int sr = t >> 2;
    const int g0 = t & 3;
    const int sw0 = ((g0 ^ (sr & 7)) << 3);
    const int sw1 = (((g0 + 4) ^ (sr & 7)) << 3);
    const unsigned short* Kg = K + (size_t)sr * 64 + g0 * 8;
    const unsigned short* Vg = Vt + (size_t)sr * 2048 + g0 * 8;

    // fragment reads: original granules quad / quad+4 of row with row&7==l15&7
    const int gq0 = ((quad ^ lo) << 3);
    const int gq1 = (((quad + 4) ^ lo) << 3);

    // P write pointers (loop-invariant): row q=l15, 8B slot (sub*4+quad)^(lo<<1)
    unsigned short* pwr = Pw + l15 * 64;
    unsigned short* pws0 = pwr + (((0 + quad) ^ (lo << 1)) << 2);
    unsigned short* pws1 = pwr + (((4 + quad) ^ (lo << 1)) << 2);
    unsigned short* pws2 = pwr + (((8 + quad) ^ (lo << 1)) << 2);
    unsigned short* pws3 = pwr + (((12 + quad) ^ (lo << 1)) << 2);

    const int nch = qt + 1;

    // prologue: chunk0 -> regsA -> buf0; chunk1 -> regsB
    uint4 ka0 = *(const uint4*)(Kg);
    uint4 ka1 = *(const uint4*)(Kg + 32);
    uint4 va0 = *(const uint4*)(Vg);
    uint4 va1 = *(const uint4*)(Vg + 32);
    *(uint4*)(Ks0 + sr * 64 + sw0) = ka0;
    *(uint4*)(Ks0 + sr * 64 + sw1) = ka1;
    *(uint4*)(Vs0 + sr * 64 + sw0) = va0;
    *(uint4*)(Vs0 + sr * 64 + sw1) = va1;
    uint4 kb0 = {}, kb1 = {}, vb0 = {}, vb1 = {};
    if (nch > 1) {
        kb0 = *(const uint4*)(Kg + 64 * 64);
        kb1 = *(const uint4*)(Kg + 64 * 64 + 32);
        vb0 = *(const uint4*)(Vg + 64);
        vb1 = *(const uint4*)(Vg + 64 + 32);
    }
    asm volatile("s_waitcnt lgkmcnt(0)" ::: "memory");
    __builtin_amdgcn_s_barrier();
    __builtin_amdgcn_sched_barrier(0);

    for (int c = 0; c < nch; c += 2) {
        attn_chunk(c, nch, qbase, c == nch - 1, Kg, Vg,
                   Ks0, Vs0, Ks1, Vs1,
                   kb0, kb1, vb0, vb1, ka0, ka1, va0, va1,
                   Pw, pws0, pws1, pws2, pws3,
                   sr, sw0, sw1, l15, quad, gq0, gq1, qf0, qf1, o, lsum);
        if (c + 1 < nch)
            attn_chunk(c + 1, nch, qbase, c + 1 == nch - 1, Kg, Vg,
                       Ks1, Vs1, Ks0, Vs0,
                       ka0, ka1, va0, va1, kb0, kb1, vb0, vb1,
                       Pw, pws0, pws1, pws2, pws3,
                       sr, sw0, sw1, l15, quad, gq0, gq1, qf0, qf1, o, lsum);
    }

    // row sum for q = l15: reduce across the 4 quad-groups (lanes l15+16k)
    float v = lsum;
    v += __shfl_xor(v, 16);
    v += __shfl_xor(v, 32);
    const float inv = 1.0f / v;

    const int b = bh >> 4, h = bh & 15;
    const int q = qbase + l15;
    unsigned short* zrow = zb + (size_t)(b * 2048 + q) * 1024 + h * 64 + quad * 4;
#pragma unroll
    for (int dt = 0; dt < 4; dt++) {
        unsigned short pk[4];
#pragma unroll
        for (int r = 0; r < 4; r++) pk[r] = f2bf(o[dt][r] * inv);
        *(uint2*)(zrow + dt * 16) = *(uint2*)pk;
    }
}

// ---------------- launch ----------------

extern "C" void kernel_launch(void* const* d_in, const int* in_sizes, int n_in,
                              void* d_out, int out_size, void* d_ws, size_t ws_size,
                              hipStream_t stream) {
    const float* x  = (const float*)d_in[0];
    const float* WQ = (const float*)d_in[1];
    const float* WK = (const float*)d_in[2];
    const float* WV = (const float*)d_in[3];
    const float* WO = (const float*)d_in[4];
    const float* bQ = (const float*)d_in[5];
    const float* bK = (const float*)d_in[6];
    const float* bV = (const float*)d_in[7];
    const float* bO = (const float*)d_in[8];
    float* out = (float*)d_out;

    char* ws = (char*)d_ws;
    unsigned short* xb   = (unsigned short*)ws;                   // 16 MB (reused as zbuf)
    unsigned short* wqkv = (unsigned short*)(ws + (16u << 20));   // 6 MB
    unsigned short* woT  = (unsigned short*)(ws + (22u << 20));   // 2 MB
    unsigned short* qws  = (unsigned short*)(ws + (24u << 20));   // 16 MB
    unsigned short* kws  = (unsigned short*)(ws + (40u << 20));   // 16 MB
    unsigned short* vtw  = (unsigned short*)(ws + (56u << 20));   // 16 MB, [bh][64][2048]
    unsigned short* zbuf = xb;                                    // x dead after gemm_qkv

    pack_all<<<24576, 256, 0, stream>>>(x, WQ, WK, WV, WO, xb, wqkv, woT);
    gemm_qkv<<<dim3(24, 64), 256, 0, stream>>>(xb, wqkv, bQ, bK, bV, qws, kws, vtw);
    attn3<<<2048, 256, 0, stream>>>(qws, kws, vtw, zbuf);
    gemm_out<<<dim3(8, 64), 256, 0, stream>>>(zbuf, woT, bO, out);
}

// Round 8
// 270.847 us; speedup vs baseline: 1.1072x; 1.1072x over previous
//
#include <hip/hip_runtime.h>
#include <hip/hip_bf16.h>
#include <math.h>

typedef __bf16 bf16_t;
typedef bf16_t bf16x8 __attribute__((ext_vector_type(8)));
typedef float f32x4 __attribute__((ext_vector_type(4)));

#define BB 4
#define SS 2048
#define HH 16
#define DMODEL 1024
#define DHEAD 64

// Q is pre-scaled by 1/sqrt(64) * log2(e) so attention probs are exp2(q.k)
#define QSCALE 0.18033688011112042f

__device__ inline unsigned short f2bf(float f) {
    union { __hip_bfloat16 h; unsigned short u; } cvt;
    cvt.h = __float2bfloat16(f);
    return cvt.u;
}

// async global->LDS, 16B per lane. LDS dest = wave-uniform base + lane*16.
__device__ __forceinline__ void gll16(const unsigned short* g, unsigned short* l) {
    __builtin_amdgcn_global_load_lds(
        (const __attribute__((address_space(1))) unsigned int*)(g),
        (__attribute__((address_space(3))) unsigned int*)(l), 16, 0, 0);
}

// ---------------- fused pack kernel ----------------
// x: coalesced f32->bf16 copy.
// W packs: 64x64 LDS-tiled TRANSPOSE (the old direct-index version read W at
// stride 256B/4KB -> ~16x HBM overfetch, ~45us hidden below the top-5 cutoff).
// f32 tile padded to 65 cols: column reads hit banks (65m+d)%32 = (m+d)%32 ->
// 2 lanes/bank = free. Reads and writes both coalesced.

__global__ void pack_all(const float* __restrict__ x,
                         const float* __restrict__ wq, const float* __restrict__ wk,
                         const float* __restrict__ wv, const float* __restrict__ wo,
                         unsigned short* __restrict__ xb, unsigned short* __restrict__ wqkv,
                         unsigned short* __restrict__ woT) {
    __shared__ float tile[64][65];
    const int t = threadIdx.x;
    const int bid = blockIdx.x;
    if (bid < 8192) {
        int i = bid * 256 + t;
        const float4 v = ((const float4*)x)[i];
        unsigned short o[4] = { f2bf(v.x), f2bf(v.y), f2bf(v.z), f2bf(v.w) };
        *(uint2*)(xb + 4 * (size_t)i) = *(uint2*)o;
        return;
    }
    // transpose tiles: src rows m (64), cols d (64) -> dst rows d, cols m
    const float* sbase;
    int sstride;
    unsigned short* dbase;   // element (d, m) -> dbase + d*1024 + m
    if (bid < 8192 + 768) {
        // WqkvT[n][k]: n = mat*1024 + h*64 + d, k = m.  W_* is [H][DM][DH].
        int b2 = bid - 8192;
        int mat = b2 >> 8, rem = b2 & 255;
        int h = rem >> 4, mt = rem & 15;
        const float* wsrc = (mat == 0) ? wq : (mat == 1) ? wk : wv;
        sbase = wsrc + (h << 16) + ((mt * 64) << 6);
        sstride = 64;
        dbase = wqkv + (size_t)(mat * 1024 + h * 64) * 1024 + mt * 64;
    } else {
        // WoT[n][k]: n = m_model, k = h*64+dh.  W_O flat is [k][n] row-major.
        int b3 = bid - 8960;
        int kt = b3 >> 4, nt = b3 & 15;
        sbase = wo + (size_t)(kt * 64) * 1024 + nt * 64;
        sstride = 1024;
        dbase = woT + (size_t)(nt * 64) * 1024 + kt * 64;
    }
    const int rr = t >> 4;           // 0..15
    const int c4 = (t & 15) * 4;     // 0..60
#pragma unroll
    for (int i = 0; i < 4; i++) {
        const int m = rr + 16 * i;
        const float4 v = *(const float4*)(sbase + (size_t)m * sstride + c4);
        tile[m][c4 + 0] = v.x;
        tile[m][c4 + 1] = v.y;
        tile[m][c4 + 2] = v.z;
        tile[m][c4 + 3] = v.w;
    }
    __syncthreads();
#pragma unroll
    for (int i = 0; i < 4; i++) {
        const int d = rr + 16 * i;
        unsigned short pk[4];
#pragma unroll
        for (int j = 0; j < 4; j++) pk[j] = f2bf(tile[c4 + j][d]);
        *(uint2*)(dbase + (size_t)d * 1024 + c4) = *(uint2*)pk;
    }
}

// ---------------- GEMM 1 (r1-proven 2-phase 128x128, ~3 blocks/CU overlap) ----------------

__global__ __launch_bounds__(256) void gemm_qkv(
    const unsigned short* __restrict__ xb,    // [8192][1024]
    const unsigned short* __restrict__ wT,    // [3072][1024]
    const float* __restrict__ bq, const float* __restrict__ bk, const float* __restrict__ bv,
    unsigned short* __restrict__ qws, unsigned short* __restrict__ kws,
    unsigned short* __restrict__ vtw)         // [64][64][2048]
{
    __shared__ __align__(16) unsigned short lA[128 * 32];   // lane-linear, no pad (gll constraint)
    __shared__ __align__(16) unsigned short lB[128 * 32];
    const int t = threadIdx.x;
    const int lane = t & 63;
    const int w = t >> 6;
    const int quad = lane >> 4;
    const int l15 = lane & 15;
    const int n0 = blockIdx.x * 128;
    const int m0 = blockIdx.y * 128;
    const int wm = (w >> 1) * 64;
    const int wn = (w & 1) * 64;
    const int mat = n0 >> 10;                 // uniform per block (1024 % 128 == 0)

    f32x4 acc[4][4] = {};

    const int srow = w * 16 + (lane >> 2);
    const int scol = (lane & 3) * 8;
    const unsigned short* Ag0 = xb + (size_t)(m0 + srow) * 1024 + scol;
    const unsigned short* Ag1 = Ag0 + (size_t)64 * 1024;
    const unsigned short* Bg0 = wT + (size_t)(n0 + srow) * 1024 + scol;
    const unsigned short* Bg1 = Bg0 + (size_t)64 * 1024;
    unsigned short* lA0 = lA + (w * 16) * 32;
    unsigned short* lA1 = lA + (64 + w * 16) * 32;
    unsigned short* lB0 = lB + (w * 16) * 32;
    unsigned short* lB1 = lB + (64 + w * 16) * 32;

    if (mat != 2) {
        // swapped operands: D[m=weight n][n=x row s]
        for (int kt = 0; kt < 1024; kt += 32) {
            __syncthreads();
            gll16(Ag0 + kt, lA0);
            gll16(Ag1 + kt, lA1);
            gll16(Bg0 + kt, lB0);
            gll16(Bg1 + kt, lB1);
            __syncthreads();
            bf16x8 af[4], bfr[4];
#pragma unroll
            for (int i = 0; i < 4; i++) {
                af[i]  = *(const bf16x8*)(lA + (wm + i * 16 + l15) * 32 + quad * 8);
                bfr[i] = *(const bf16x8*)(lB + (wn + i * 16 + l15) * 32 + quad * 8);
            }
#pragma unroll
            for (int i = 0; i < 4; i++)
#pragma unroll
                for (int j = 0; j < 4; j++)
                    acc[i][j] = __builtin_amdgcn_mfma_f32_16x16x32_bf16(bfr[j], af[i], acc[i][j], 0, 0, 0);
        }
        // epilogue: lane holds 4 consecutive d at fixed s -> uint2 stores
        const int b = m0 >> 11;
        const float* bias_p = (mat == 0) ? bq : bk;
        const float scale = (mat == 0) ? QSCALE : 1.0f;   // fold softmax scale+log2e into Q
        unsigned short* dst = (mat == 0) ? qws : kws;
#pragma unroll
        for (int j = 0; j < 4; j++) {
            const int noff = wn + j * 16 + quad * 4;          // 0..124
            const int h = noff >> 6;
            const int hglob = ((n0 & 1023) >> 6) + h;
            const int dbase = noff & 63;
            const float4 bv4 = *(const float4*)(bias_p + hglob * 64 + dbase);
            const float bias_r[4] = { bv4.x, bv4.y, bv4.z, bv4.w };
#pragma unroll
            for (int i = 0; i < 4; i++) {
                const int s = (m0 & 2047) + wm + i * 16 + l15;
                unsigned short pk[4];
#pragma unroll
                for (int r = 0; r < 4; r++) pk[r] = f2bf((acc[i][j][r] + bias_r[r]) * scale);
                *(uint2*)(dst + (size_t)((b * 16 + hglob) * 2048 + s) * 64 + dbase) = *(uint2*)pk;
            }
        }
    } else {
        // normal order: D[m=x row s][n=weight] -> 4 consecutive s at fixed d -> uint2 into V^T
        for (int kt = 0; kt < 1024; kt += 32) {
            __syncthreads();
            gll16(Ag0 + kt, lA0);
            gll16(Ag1 + kt, lA1);
            gll16(Bg0 + kt, lB0);
            gll16(Bg1 + kt, lB1);
            __syncthreads();
            bf16x8 af[4], bfr[4];
#pragma unroll
            for (int i = 0; i < 4; i++) {
                af[i]  = *(const bf16x8*)(lA + (wm + i * 16 + l15) * 32 + quad * 8);
                bfr[i] = *(const bf16x8*)(lB + (wn + i * 16 + l15) * 32 + quad * 8);
            }
#pragma unroll
            for (int i = 0; i < 4; i++)
#pragma unroll
                for (int j = 0; j < 4; j++)
                    acc[i][j] = __builtin_amdgcn_mfma_f32_16x16x32_bf16(af[i], bfr[j], acc[i][j], 0, 0, 0);
        }
        const int b = m0 >> 11;
#pragma unroll
        for (int j = 0; j < 4; j++) {
            const int n1 = (n0 & 1023) + wn + j * 16 + l15;
            const int h = n1 >> 6, d = n1 & 63;
            const float bias = bv[h * 64 + d];
#pragma unroll
            for (int i = 0; i < 4; i++) {
                const int s0 = (m0 & 2047) + wm + i * 16 + quad * 4;
                unsigned short pk[4];
#pragma unroll
                for (int r = 0; r < 4; r++) pk[r] = f2bf(acc[i][j][r] + bias);
                *(uint2*)(vtw + ((size_t)(b * 16 + h) * 64 + d) * 2048 + s0) = *(uint2*)pk;
            }
        }
    }
}

// ---------------- GEMM 2 (r1-proven 2-phase 128x128): out = z @ WoT^T + bO ----------------

__global__ __launch_bounds__(256) void gemm_out(
    const unsigned short* __restrict__ zb,    // [8192][1024]
    const unsigned short* __restrict__ wT,    // [1024][1024]
    const float* __restrict__ bo,
    float* __restrict__ out)
{
    __shared__ __align__(16) unsigned short lA[128 * 32];
    __shared__ __align__(16) unsigned short lB[128 * 32];
    const int t = threadIdx.x;
    const int lane = t & 63;
    const int w = t >> 6;
    const int quad = lane >> 4;
    const int l15 = lane & 15;
    const int n0 = blockIdx.x * 128;
    const int m0 = blockIdx.y * 128;
    const int wm = (w >> 1) * 64;
    const int wn = (w & 1) * 64;

    f32x4 acc[4][4] = {};

    const int srow = w * 16 + (lane >> 2);
    const int scol = (lane & 3) * 8;
    const unsigned short* Ag0 = zb + (size_t)(m0 + srow) * 1024 + scol;
    const unsigned short* Ag1 = Ag0 + (size_t)64 * 1024;
    const unsigned short* Bg0 = wT + (size_t)(n0 + srow) * 1024 + scol;
    const unsigned short* Bg1 = Bg0 + (size_t)64 * 1024;
    unsigned short* lA0 = lA + (w * 16) * 32;
    unsigned short* lA1 = lA + (64 + w * 16) * 32;
    unsigned short* lB0 = lB + (w * 16) * 32;
    unsigned short* lB1 = lB + (64 + w * 16) * 32;

    for (int kt = 0; kt < 1024; kt += 32) {
        __syncthreads();
        gll16(Ag0 + kt, lA0);
        gll16(Ag1 + kt, lA1);
        gll16(Bg0 + kt, lB0);
        gll16(Bg1 + kt, lB1);
        __syncthreads();
        bf16x8 af[4], bfr[4];
#pragma unroll
        for (int i = 0; i < 4; i++) {
            af[i]  = *(const bf16x8*)(lA + (wm + i * 16 + l15) * 32 + quad * 8);
            bfr[i] = *(const bf16x8*)(lB + (wn + i * 16 + l15) * 32 + quad * 8);
        }
#pragma unroll
        for (int i = 0; i < 4; i++)
#pragma unroll
            for (int j = 0; j < 4; j++)
                acc[i][j] = __builtin_amdgcn_mfma_f32_16x16x32_bf16(bfr[j], af[i], acc[i][j], 0, 0, 0);
    }

    // swapped D: lane holds 4 consecutive n at fixed s -> float4 stores
#pragma unroll
    for (int j = 0; j < 4; j++) {
        const int nbase = n0 + wn + j * 16 + quad * 4;
        const float4 bv4 = *(const float4*)(bo + nbase);
#pragma unroll
        for (int i = 0; i < 4; i++) {
            const int s = m0 + wm + i * 16 + l15;
            float4 v;
            v.x = acc[i][j][0] + bv4.x;
            v.y = acc[i][j][1] + bv4.y;
            v.z = acc[i][j][2] + bv4.z;
            v.w = acc[i][j][3] + bv4.w;
            *(float4*)(out + (size_t)s * 1024 + nbase) = v;
        }
    }
}

// ---------------- attention v6 (r6-measured best; v7 dbuf reverted) ----------------
// mfma(K,Q) gives S[key][q=l15]: lane holds 4 CONSECUTIVE keys at fixed q, so the
// P store is 4x ds_write_b64 to loop-invariant addresses. 8B-slot swizzle
// slot^=(lo<<1) keeps the b128 read addresses (granule^lo) valid. Row-sum is a
// single scalar per lane + shfl_xor(16/32).

__global__ __launch_bounds__(256) void attn3(
    const unsigned short* __restrict__ qws,
    const unsigned short* __restrict__ kws,
    const unsigned short* __restrict__ vtw,   // [bh][64][2048]
    unsigned short* __restrict__ zb)          // [8192][1024], col = h*64+d
{
    __shared__ __align__(16) unsigned short Ks[64 * 64];
    __shared__ __align__(16) unsigned short Vs[64 * 64];    // [d][key]
    __shared__ __align__(16) unsigned short Ps[4 * 16 * 64]; // per-wave [q=16][key=64]

    const int t = threadIdx.x;
    const int lane = t & 63;
    const int w = t >> 6;
    const int quad = lane >> 4;
    const int l15 = lane & 15;
    const int lo = l15 & 7;

    const int qt = 31 - (blockIdx.x >> 6);   // longest blocks dispatched first
    const int bh = blockIdx.x & 63;
    const int q0 = qt * 64;
    const int qbase = q0 + w * 16;
    const size_t base = (size_t)bh * SS * DHEAD;
    const unsigned short* Q = qws + base;
    const unsigned short* K = kws + base;
    const unsigned short* Vt = vtw + base;   // [64][2048]

    bf16x8 qf0 = *(const bf16x8*)(Q + (size_t)(qbase + l15) * 64 + quad * 8);
    bf16x8 qf1 = *(const bf16x8*)(Q + (size_t)(qbase + l15) * 64 + 32 + quad * 8);

    f32x4 o[4] = {};          // swapped PV: o[dt] rows = d (dt*16+quad*4+r), col = q (l15)
    float lsum = 0.f;         // row-sum for q = qbase + l15
    unsigned short* Pw = Ps + w * 16 * 64;

    // staging: thread t covers row sr, original col-granules (t&3) and (t&3)+4
    const int sr = t >> 2;
    const int g0 = t & 3;
    const int sw0 = ((g0 ^ (sr & 7)) << 3);
    const int sw1 = (((g0 + 4) ^ (sr & 7)) << 3);
    unsigned short* ksw = Ks + sr * 64;
    unsigned short* vsw = Vs + sr * 64;
    const unsigned short* Kg = K + (size_t)sr * 64 + g0 * 8;
    const unsigned short* Vg = Vt + (size_t)sr * 2048 + g0 * 8;

    // fragment reads: original granules quad / quad+4 of row with row&7==l15&7
    const int gq0 = ((quad ^ lo) << 3);
    const int gq1 = (((quad + 4) ^ lo) << 3);

    // P write pointers (loop-invariant): row q=l15, 8B slot (sub*4+quad)^(lo<<1)
    unsigned short* pwr = Pw + l15 * 64;
    unsigned short* pws0 = pwr + (((0 + quad) ^ (lo << 1)) << 2);
    unsigned short* pws1 = pwr + (((4 + quad) ^ (lo << 1)) << 2);
    unsigned short* pws2 = pwr + (((8 + quad) ^ (lo << 1)) << 2);
    unsigned short* pws3 = pwr + (((12 + quad) ^ (lo << 1)) << 2);

    const int nch = qt + 1;

    // prologue: prefetch chunk 0 into registers
    uint4 kr0 = *(const uint4*)(Kg);
    uint4 kr1 = *(const uint4*)(Kg + 32);
    uint4 vr0 = *(const uint4*)(Vg);
    uint4 vr1 = *(const uint4*)(Vg + 32);

    for (int c = 0; c < nch; c++) {
        __builtin_amdgcn_sched_barrier(0);
        __builtin_amdgcn_s_barrier();          // LDS free: all waves consumed chunk c-1
        *(uint4*)(ksw + sw0) = kr0;
        *(uint4*)(ksw + sw1) = kr1;
        *(uint4*)(vsw + sw0) = vr0;
        *(uint4*)(vsw + sw1) = vr1;
        if (c + 1 < nch) {                     // issue next chunk's loads; NOT waited here
            const unsigned short* kp = Kg + (size_t)(c + 1) * 64 * 64;
            const unsigned short* vp = Vg + (size_t)(c + 1) * 64;
            kr0 = *(const uint4*)(kp);
            kr1 = *(const uint4*)(kp + 32);
            vr0 = *(const uint4*)(vp);
            vr1 = *(const uint4*)(vp + 32);
        }
        asm volatile("s_waitcnt lgkmcnt(0)" ::: "memory");   // my ds_writes done (vmcnt stays)
        __builtin_amdgcn_s_barrier();          // LDS ready
        __builtin_amdgcn_sched_barrier(0);

        // scores, SWAPPED: A=K, B=Q -> D[row=key quad*4+r][col=q l15]
        f32x4 s[4];
        __builtin_amdgcn_s_setprio(1);
#pragma unroll
        for (int sub = 0; sub < 4; sub++) {
            const unsigned short* kr = Ks + (sub * 16 + l15) * 64;
            bf16x8 kf0 = *(const bf16x8*)(kr + gq0);
            bf16x8 kf1 = *(const bf16x8*)(kr + gq1);
            f32x4 sv = {};
            sv = __builtin_amdgcn_mfma_f32_16x16x32_bf16(kf0, qf0, sv, 0, 0, 0);
            sv = __builtin_amdgcn_mfma_f32_16x16x32_bf16(kf1, qf1, sv, 0, 0, 0);
            s[sub] = sv;
        }
        __builtin_amdgcn_s_setprio(0);

        // fixed-max softmax: p = exp2(s); lane covers keys k0..k0+3 at q=qbase+l15
        const int kb = c * 64;
        if (c == nch - 1) {
            const int qg = qbase + l15;
#pragma unroll
            for (int sub = 0; sub < 4; sub++) {
                const int k0 = kb + sub * 16 + quad * 4;
                unsigned short pk[4];
#pragma unroll
                for (int r = 0; r < 4; r++) {
                    float p = (k0 + r > qg) ? 0.f : exp2f(s[sub][r]);
                    lsum += p;
                    pk[r] = f2bf(p);
                }
                unsigned short* wp = (sub == 0) ? pws0 : (sub == 1) ? pws1 : (sub == 2) ? pws2 : pws3;
                *(uint2*)wp = *(uint2*)pk;
            }
        } else {
#pragma unroll
            for (int sub = 0; sub < 4; sub++) {
                unsigned short pk[4];
#pragma unroll
                for (int r = 0; r < 4; r++) {
                    float p = exp2f(s[sub][r]);
                    lsum += p;
                    pk[r] = f2bf(p);
                }
                unsigned short* wp = (sub == 0) ? pws0 : (sub == 1) ? pws1 : (sub == 2) ? pws2 : pws3;
                *(uint2*)wp = *(uint2*)pk;
            }
        }
        // wave-private write -> fragment read (same wave, cross-lane): drain DS
        asm volatile("s_waitcnt lgkmcnt(0)" ::: "memory");
        bf16x8 pf0 = *(const bf16x8*)(Pw + l15 * 64 + gq0);
        bf16x8 pf1 = *(const bf16x8*)(Pw + l15 * 64 + gq1);
        __builtin_amdgcn_s_setprio(1);
#pragma unroll
        for (int dt = 0; dt < 4; dt++) {
            const unsigned short* vrp = Vs + (dt * 16 + l15) * 64;
            bf16x8 vf0 = *(const bf16x8*)(vrp + gq0);
            bf16x8 vf1 = *(const bf16x8*)(vrp + gq1);
            // swapped: A=V (m=d), B=P (n=q)
            o[dt] = __builtin_amdgcn_mfma_f32_16x16x32_bf16(vf0, pf0, o[dt], 0, 0, 0);
            o[dt] = __builtin_amdgcn_mfma_f32_16x16x32_bf16(vf1, pf1, o[dt], 0, 0, 0);
        }
        __builtin_amdgcn_s_setprio(0);
    }

    // row sum for q = l15: reduce across the 4 quad-groups (lanes l15+16k)
    float v = lsum;
    v += __shfl_xor(v, 16);
    v += __shfl_xor(v, 32);
    const float inv = 1.0f / v;

    const int b = bh >> 4, h = bh & 15;
    const int q = qbase + l15;
    unsigned short* zrow = zb + (size_t)(b * 2048 + q) * 1024 + h * 64 + quad * 4;
#pragma unroll
    for (int dt = 0; dt < 4; dt++) {
        unsigned short pk[4];
#pragma unroll
        for (int r = 0; r < 4; r++) pk[r] = f2bf(o[dt][r] * inv);
        *(uint2*)(zrow + dt * 16) = *(uint2*)pk;
    }
}

// ---------------- launch ----------------

extern "C" void kernel_launch(void* const* d_in, const int* in_sizes, int n_in,
                              void* d_out, int out_size, void* d_ws, size_t ws_size,
                              hipStream_t stream) {
    const float* x  = (const float*)d_in[0];
    const float* WQ = (const float*)d_in[1];
    const float* WK = (const float*)d_in[2];
    const float* WV = (const float*)d_in[3];
    const float* WO = (const float*)d_in[4];
    const float* bQ = (const float*)d_in[5];
    const float* bK = (const float*)d_in[6];
    const float* bV = (const float*)d_in[7];
    const float* bO = (const float*)d_in[8];
    float* out = (float*)d_out;

    char* ws = (char*)d_ws;
    unsigned short* xb   = (unsigned short*)ws;                   // 16 MB (reused as zbuf)
    unsigned short* wqkv = (unsigned short*)(ws + (16u << 20));   // 6 MB
    unsigned short* woT  = (unsigned short*)(ws + (22u << 20));   // 2 MB
    unsigned short* qws  = (unsigned short*)(ws + (24u << 20));   // 16 MB
    unsigned short* kws  = (unsigned short*)(ws + (40u << 20));   // 16 MB
    unsigned short* vtw  = (unsigned short*)(ws + (56u << 20));   // 16 MB, [bh][64][2048]
    unsigned short* zbuf = xb;                                    // x dead after gemm_qkv

    pack_all<<<9216, 256, 0, stream>>>(x, WQ, WK, WV, WO, xb, wqkv, woT);
    gemm_qkv<<<dim3(24, 64), 256, 0, stream>>>(xb, wqkv, bQ, bK, bV, qws, kws, vtw);
    attn3<<<2048, 256, 0, stream>>>(qws, kws, vtw, zbuf);
    gemm_out<<<dim3(8, 64), 256, 0, stream>>>(zbuf, woT, bO, out);
}

// Round 9
// 266.657 us; speedup vs baseline: 1.1246x; 1.0157x over previous
//
#include <hip/hip_runtime.h>
#include <hip/hip_bf16.h>
#include <math.h>

typedef __bf16 bf16_t;
typedef bf16_t bf16x8 __attribute__((ext_vector_type(8)));
typedef float f32x4 __attribute__((ext_vector_type(4)));

#define BB 4
#define SS 2048
#define HH 16
#define DMODEL 1024
#define DHEAD 64

// Q is pre-scaled by 1/sqrt(64) * log2(e) so attention probs are exp2(q.k)
#define QSCALE 0.18033688011112042f

__device__ inline unsigned short f2bf(float f) {
    union { __hip_bfloat16 h; unsigned short u; } cvt;
    cvt.h = __float2bfloat16(f);
    return cvt.u;
}

// async global->LDS, 16B per lane. LDS dest = wave-uniform base + lane*16.
__device__ __forceinline__ void gll16(const unsigned short* g, unsigned short* l) {
    __builtin_amdgcn_global_load_lds(
        (const __attribute__((address_space(1))) unsigned int*)(g),
        (__attribute__((address_space(3))) unsigned int*)(l), 16, 0, 0);
}

// ---------------- fused pack kernel (r8-measured) ----------------

__global__ void pack_all(const float* __restrict__ x,
                         const float* __restrict__ wq, const float* __restrict__ wk,
                         const float* __restrict__ wv, const float* __restrict__ wo,
                         unsigned short* __restrict__ xb, unsigned short* __restrict__ wqkv,
                         unsigned short* __restrict__ woT) {
    __shared__ float tile[64][65];
    const int t = threadIdx.x;
    const int bid = blockIdx.x;
    if (bid < 8192) {
        int i = bid * 256 + t;
        const float4 v = ((const float4*)x)[i];
        unsigned short o[4] = { f2bf(v.x), f2bf(v.y), f2bf(v.z), f2bf(v.w) };
        *(uint2*)(xb + 4 * (size_t)i) = *(uint2*)o;
        return;
    }
    // transpose tiles: src rows m (64), cols d (64) -> dst rows d, cols m
    const float* sbase;
    int sstride;
    unsigned short* dbase;   // element (d, m) -> dbase + d*1024 + m
    if (bid < 8192 + 768) {
        int b2 = bid - 8192;
        int mat = b2 >> 8, rem = b2 & 255;
        int h = rem >> 4, mt = rem & 15;
        const float* wsrc = (mat == 0) ? wq : (mat == 1) ? wk : wv;
        sbase = wsrc + (h << 16) + ((mt * 64) << 6);
        sstride = 64;
        dbase = wqkv + (size_t)(mat * 1024 + h * 64) * 1024 + mt * 64;
    } else {
        int b3 = bid - 8960;
        int kt = b3 >> 4, nt = b3 & 15;
        sbase = wo + (size_t)(kt * 64) * 1024 + nt * 64;
        sstride = 1024;
        dbase = woT + (size_t)(nt * 64) * 1024 + kt * 64;
    }
    const int rr = t >> 4;           // 0..15
    const int c4 = (t & 15) * 4;     // 0..60
#pragma unroll
    for (int i = 0; i < 4; i++) {
        const int m = rr + 16 * i;
        const float4 v = *(const float4*)(sbase + (size_t)m * sstride + c4);
        tile[m][c4 + 0] = v.x;
        tile[m][c4 + 1] = v.y;
        tile[m][c4 + 2] = v.z;
        tile[m][c4 + 3] = v.w;
    }
    __syncthreads();
#pragma unroll
    for (int i = 0; i < 4; i++) {
        const int d = rr + 16 * i;
        unsigned short pk[4];
#pragma unroll
        for (int j = 0; j < 4; j++) pk[j] = f2bf(tile[c4 + j][d]);
        *(uint2*)(dbase + (size_t)d * 1024 + c4) = *(uint2*)pk;
    }
}

// ---------------- GEMM 1: 2-phase 128x128, BK=64, swizzled staging ----------------
// vs r8 (BK=32): HALVES the per-block barrier/drain count (32->16) -- the m233
// decomposition says the fixed per-barrier vmcnt(0) drain dominates the 2-phase
// stall. LDS 32 KiB (no occupancy cliff). 128B rows would be a 16-way read
// conflict, so staging uses the r2/r5-verified pre-swizzled global source
// (granule^(row&7), measured 0 conflicts on this problem) + swizzled b128 reads.

__global__ __launch_bounds__(256) void gemm_qkv(
    const unsigned short* __restrict__ xb,    // [8192][1024]
    const unsigned short* __restrict__ wT,    // [3072][1024]
    const float* __restrict__ bq, const float* __restrict__ bk, const float* __restrict__ bv,
    unsigned short* __restrict__ qws, unsigned short* __restrict__ kws,
    unsigned short* __restrict__ vtw)         // [64][64][2048]
{
    __shared__ __align__(16) unsigned short lA[128 * 64];   // 16 KiB
    __shared__ __align__(16) unsigned short lB[128 * 64];   // 16 KiB
    const int t = threadIdx.x;
    const int lane = t & 63;
    const int w = t >> 6;
    const int quad = lane >> 4;
    const int l15 = lane & 15;
    const int lo = l15 & 7;
    const int n0 = blockIdx.x * 128;
    const int m0 = blockIdx.y * 128;
    const int wm = (w >> 1) * 64;
    const int wn = (w & 1) * 64;
    const int mat = n0 >> 10;                 // uniform per block (1024 % 128 == 0)

    f32x4 acc[4][4] = {};

    // staging: wave w covers rows {c*32 + w*8 + sr8}, lane's global col granule
    // pre-swizzled by ^sr8 so the linear gll16 dest realizes the XOR layout
    const int sr8 = lane >> 3;                // 0..7
    const int g8 = lane & 7;                  // 0..7
    const size_t soff = (size_t)(w * 8 + sr8) * 1024 + (size_t)(((g8 ^ sr8)) << 3);
    const unsigned short* Ab = xb + (size_t)m0 * 1024 + soff;
    const unsigned short* Bb = wT + (size_t)n0 * 1024 + soff;
    unsigned short* lAw = lA + (w * 8) * 64;
    unsigned short* lBw = lB + (w * 8) * 64;

    // fragment read cols: original granule q of row r lives at LDS granule q^(r&7)
    const int c0 = ((quad ^ lo)) << 3;
    const int c1 = (((4 | quad) ^ lo)) << 3;

    if (mat != 2) {
        // swapped operands: D[m=weight n][n=x row s]
        for (int kt = 0; kt < 1024; kt += 64) {
            __syncthreads();
            gll16(Ab + kt,               lAw);
            gll16(Ab + 32 * 1024 + kt,   lAw + 32 * 64);
            gll16(Ab + 64 * 1024 + kt,   lAw + 64 * 64);
            gll16(Ab + 96 * 1024 + kt,   lAw + 96 * 64);
            gll16(Bb + kt,               lBw);
            gll16(Bb + 32 * 1024 + kt,   lBw + 32 * 64);
            gll16(Bb + 64 * 1024 + kt,   lBw + 64 * 64);
            gll16(Bb + 96 * 1024 + kt,   lBw + 96 * 64);
            __syncthreads();
            bf16x8 af[4][2], bfr[4][2];
#pragma unroll
            for (int i = 0; i < 4; i++) {
                af[i][0]  = *(const bf16x8*)(lA + (wm + i * 16 + l15) * 64 + c0);
                af[i][1]  = *(const bf16x8*)(lA + (wm + i * 16 + l15) * 64 + c1);
                bfr[i][0] = *(const bf16x8*)(lB + (wn + i * 16 + l15) * 64 + c0);
                bfr[i][1] = *(const bf16x8*)(lB + (wn + i * 16 + l15) * 64 + c1);
            }
#pragma unroll
            for (int i = 0; i < 4; i++)
#pragma unroll
                for (int j = 0; j < 4; j++) {
                    acc[i][j] = __builtin_amdgcn_mfma_f32_16x16x32_bf16(bfr[j][0], af[i][0], acc[i][j], 0, 0, 0);
                    acc[i][j] = __builtin_amdgcn_mfma_f32_16x16x32_bf16(bfr[j][1], af[i][1], acc[i][j], 0, 0, 0);
                }
        }
        // epilogue: lane holds 4 consecutive d at fixed s -> uint2 stores
        const int b = m0 >> 11;
        const float* bias_p = (mat == 0) ? bq : bk;
        const float scale = (mat == 0) ? QSCALE : 1.0f;   // fold softmax scale+log2e into Q
        unsigned short* dst = (mat == 0) ? qws : kws;
#pragma unroll
        for (int j = 0; j < 4; j++) {
            const int noff = wn + j * 16 + quad * 4;          // 0..124
            const int h = noff >> 6;
            const int hglob = ((n0 & 1023) >> 6) + h;
            const int dbase = noff & 63;
            const float4 bv4 = *(const float4*)(bias_p + hglob * 64 + dbase);
            const float bias_r[4] = { bv4.x, bv4.y, bv4.z, bv4.w };
#pragma unroll
            for (int i = 0; i < 4; i++) {
                const int s = (m0 & 2047) + wm + i * 16 + l15;
                unsigned short pk[4];
#pragma unroll
                for (int r = 0; r < 4; r++) pk[r] = f2bf((acc[i][j][r] + bias_r[r]) * scale);
                *(uint2*)(dst + (size_t)((b * 16 + hglob) * 2048 + s) * 64 + dbase) = *(uint2*)pk;
            }
        }
    } else {
        // normal order: D[m=x row s][n=weight] -> 4 consecutive s at fixed d -> uint2 into V^T
        for (int kt = 0; kt < 1024; kt += 64) {
            __syncthreads();
            gll16(Ab + kt,               lAw);
            gll16(Ab + 32 * 1024 + kt,   lAw + 32 * 64);
            gll16(Ab + 64 * 1024 + kt,   lAw + 64 * 64);
            gll16(Ab + 96 * 1024 + kt,   lAw + 96 * 64);
            gll16(Bb + kt,               lBw);
            gll16(Bb + 32 * 1024 + kt,   lBw + 32 * 64);
            gll16(Bb + 64 * 1024 + kt,   lBw + 64 * 64);
            gll16(Bb + 96 * 1024 + kt,   lBw + 96 * 64);
            __syncthreads();
            bf16x8 af[4][2], bfr[4][2];
#pragma unroll
            for (int i = 0; i < 4; i++) {
                af[i][0]  = *(const bf16x8*)(lA + (wm + i * 16 + l15) * 64 + c0);
                af[i][1]  = *(const bf16x8*)(lA + (wm + i * 16 + l15) * 64 + c1);
                bfr[i][0] = *(const bf16x8*)(lB + (wn + i * 16 + l15) * 64 + c0);
                bfr[i][1] = *(const bf16x8*)(lB + (wn + i * 16 + l15) * 64 + c1);
            }
#pragma unroll
            for (int i = 0; i < 4; i++)
#pragma unroll
                for (int j = 0; j < 4; j++) {
                    acc[i][j] = __builtin_amdgcn_mfma_f32_16x16x32_bf16(af[i][0], bfr[j][0], acc[i][j], 0, 0, 0);
                    acc[i][j] = __builtin_amdgcn_mfma_f32_16x16x32_bf16(af[i][1], bfr[j][1], acc[i][j], 0, 0, 0);
                }
        }
        const int b = m0 >> 11;
#pragma unroll
        for (int j = 0; j < 4; j++) {
            const int n1 = (n0 & 1023) + wn + j * 16 + l15;
            const int h = n1 >> 6, d = n1 & 63;
            const float bias = bv[h * 64 + d];
#pragma unroll
            for (int i = 0; i < 4; i++) {
                const int s0 = (m0 & 2047) + wm + i * 16 + quad * 4;
                unsigned short pk[4];
#pragma unroll
                for (int r = 0; r < 4; r++) pk[r] = f2bf(acc[i][j][r] + bias);
                *(uint2*)(vtw + ((size_t)(b * 16 + h) * 64 + d) * 2048 + s0) = *(uint2*)pk;
            }
        }
    }
}

// ---------------- GEMM 2: 2-phase 128x128, BK=64, swizzled (same scheme) ----------------

__global__ __launch_bounds__(256) void gemm_out(
    const unsigned short* __restrict__ zb,    // [8192][1024]
    const unsigned short* __restrict__ wT,    // [1024][1024]
    const float* __restrict__ bo,
    float* __restrict__ out)
{
    __shared__ __align__(16) unsigned short lA[128 * 64];
    __shared__ __align__(16) unsigned short lB[128 * 64];
    const int t = threadIdx.x;
    const int lane = t & 63;
    const int w = t >> 6;
    const int quad = lane >> 4;
    const int l15 = lane & 15;
    const int lo = l15 & 7;
    const int n0 = blockIdx.x * 128;
    const int m0 = blockIdx.y * 128;
    const int wm = (w >> 1) * 64;
    const int wn = (w & 1) * 64;

    f32x4 acc[4][4] = {};

    const int sr8 = lane >> 3;
    const int g8 = lane & 7;
    const size_t soff = (size_t)(w * 8 + sr8) * 1024 + (size_t)(((g8 ^ sr8)) << 3);
    const unsigned short* Ab = zb + (size_t)m0 * 1024 + soff;
    const unsigned short* Bb = wT + (size_t)n0 * 1024 + soff;
    unsigned short* lAw = lA + (w * 8) * 64;
    unsigned short* lBw = lB + (w * 8) * 64;

    const int c0 = ((quad ^ lo)) << 3;
    const int c1 = (((4 | quad) ^ lo)) << 3;

    for (int kt = 0; kt < 1024; kt += 64) {
        __syncthreads();
        gll16(Ab + kt,               lAw);
        gll16(Ab + 32 * 1024 + kt,   lAw + 32 * 64);
        gll16(Ab + 64 * 1024 + kt,   lAw + 64 * 64);
        gll16(Ab + 96 * 1024 + kt,   lAw + 96 * 64);
        gll16(Bb + kt,               lBw);
        gll16(Bb + 32 * 1024 + kt,   lBw + 32 * 64);
        gll16(Bb + 64 * 1024 + kt,   lBw + 64 * 64);
        gll16(Bb + 96 * 1024 + kt,   lBw + 96 * 64);
        __syncthreads();
        bf16x8 af[4][2], bfr[4][2];
#pragma unroll
        for (int i = 0; i < 4; i++) {
            af[i][0]  = *(const bf16x8*)(lA + (wm + i * 16 + l15) * 64 + c0);
            af[i][1]  = *(const bf16x8*)(lA + (wm + i * 16 + l15) * 64 + c1);
            bfr[i][0] = *(const bf16x8*)(lB + (wn + i * 16 + l15) * 64 + c0);
            bfr[i][1] = *(const bf16x8*)(lB + (wn + i * 16 + l15) * 64 + c1);
        }
#pragma unroll
        for (int i = 0; i < 4; i++)
#pragma unroll
            for (int j = 0; j < 4; j++) {
                acc[i][j] = __builtin_amdgcn_mfma_f32_16x16x32_bf16(bfr[j][0], af[i][0], acc[i][j], 0, 0, 0);
                acc[i][j] = __builtin_amdgcn_mfma_f32_16x16x32_bf16(bfr[j][1], af[i][1], acc[i][j], 0, 0, 0);
            }
    }

    // swapped D: lane holds 4 consecutive n at fixed s -> float4 stores
#pragma unroll
    for (int j = 0; j < 4; j++) {
        const int nbase = n0 + wn + j * 16 + quad * 4;
        const float4 bv4 = *(const float4*)(bo + nbase);
#pragma unroll
        for (int i = 0; i < 4; i++) {
            const int s = m0 + wm + i * 16 + l15;
            float4 v;
            v.x = acc[i][j][0] + bv4.x;
            v.y = acc[i][j][1] + bv4.y;
            v.z = acc[i][j][2] + bv4.z;
            v.w = acc[i][j][3] + bv4.w;
            *(float4*)(out + (size_t)s * 1024 + nbase) = v;
        }
    }
}

// ---------------- attention v6 (r6/r8-measured best; frozen) ----------------

__global__ __launch_bounds__(256) void attn3(
    const unsigned short* __restrict__ qws,
    const unsigned short* __restrict__ kws,
    const unsigned short* __restrict__ vtw,   // [bh][64][2048]
    unsigned short* __restrict__ zb)          // [8192][1024], col = h*64+d
{
    __shared__ __align__(16) unsigned short Ks[64 * 64];
    __shared__ __align__(16) unsigned short Vs[64 * 64];    // [d][key]
    __shared__ __align__(16) unsigned short Ps[4 * 16 * 64]; // per-wave [q=16][key=64]

    const int t = threadIdx.x;
    const int lane = t & 63;
    const int w = t >> 6;
    const int quad = lane >> 4;
    const int l15 = lane & 15;
    const int lo = l15 & 7;

    const int qt = 31 - (blockIdx.x >> 6);   // longest blocks dispatched first
    const int bh = blockIdx.x & 63;
    const int q0 = qt * 64;
    const int qbase = q0 + w * 16;
    const size_t base = (size_t)bh * SS * DHEAD;
    const unsigned short* Q = qws + base;
    const unsigned short* K = kws + base;
    const unsigned short* Vt = vtw + base;   // [64][2048]

    bf16x8 qf0 = *(const bf16x8*)(Q + (size_t)(qbase + l15) * 64 + quad * 8);
    bf16x8 qf1 = *(const bf16x8*)(Q + (size_t)(qbase + l15) * 64 + 32 + quad * 8);

    f32x4 o[4] = {};          // swapped PV: o[dt] rows = d (dt*16+quad*4+r), col = q (l15)
    float lsum = 0.f;         // row-sum for q = qbase + l15
    unsigned short* Pw = Ps + w * 16 * 64;

    // staging: thread t covers row sr, original col-granules (t&3) and (t&3)+4
    const int sr = t >> 2;
    const int g0 = t & 3;
    const int sw0 = ((g0 ^ (sr & 7)) << 3);
    const int sw1 = (((g0 + 4) ^ (sr & 7)) << 3);
    unsigned short* ksw = Ks + sr * 64;
    unsigned short* vsw = Vs + sr * 64;
    const unsigned short* Kg = K + (size_t)sr * 64 + g0 * 8;
    const unsigned short* Vg = Vt + (size_t)sr * 2048 + g0 * 8;

    // fragment reads: original granules quad / quad+4 of row with row&7==l15&7
    const int gq0 = ((quad ^ lo) << 3);
    const int gq1 = (((quad + 4) ^ lo) << 3);

    // P write pointers (loop-invariant): row q=l15, 8B slot (sub*4+quad)^(lo<<1)
    unsigned short* pwr = Pw + l15 * 64;
    unsigned short* pws0 = pwr + (((0 + quad) ^ (lo << 1)) << 2);
    unsigned short* pws1 = pwr + (((4 + quad) ^ (lo << 1)) << 2);
    unsigned short* pws2 = pwr + (((8 + quad) ^ (lo << 1)) << 2);
    unsigned short* pws3 = pwr + (((12 + quad) ^ (lo << 1)) << 2);

    const int nch = qt + 1;

    // prologue: prefetch chunk 0 into registers
    uint4 kr0 = *(const uint4*)(Kg);
    uint4 kr1 = *(const uint4*)(Kg + 32);
    uint4 vr0 = *(const uint4*)(Vg);
    uint4 vr1 = *(const uint4*)(Vg + 32);

    for (int c = 0; c < nch; c++) {
        __builtin_amdgcn_sched_barrier(0);
        __builtin_amdgcn_s_barrier();          // LDS free: all waves consumed chunk c-1
        *(uint4*)(ksw + sw0) = kr0;
        *(uint4*)(ksw + sw1) = kr1;
        *(uint4*)(vsw + sw0) = vr0;
        *(uint4*)(vsw + sw1) = vr1;
        if (c + 1 < nch) {                     // issue next chunk's loads; NOT waited here
            const unsigned short* kp = Kg + (size_t)(c + 1) * 64 * 64;
            const unsigned short* vp = Vg + (size_t)(c + 1) * 64;
            kr0 = *(const uint4*)(kp);
            kr1 = *(const uint4*)(kp + 32);
            vr0 = *(const uint4*)(vp);
            vr1 = *(const uint4*)(vp + 32);
        }
        asm volatile("s_waitcnt lgkmcnt(0)" ::: "memory");   // my ds_writes done (vmcnt stays)
        __builtin_amdgcn_s_barrier();          // LDS ready
        __builtin_amdgcn_sched_barrier(0);

        // scores, SWAPPED: A=K, B=Q -> D[row=key quad*4+r][col=q l15]
        f32x4 s[4];
        __builtin_amdgcn_s_setprio(1);
#pragma unroll
        for (int sub = 0; sub < 4; sub++) {
            const unsigned short* kr = Ks + (sub * 16 + l15) * 64;
            bf16x8 kf0 = *(const bf16x8*)(kr + gq0);
            bf16x8 kf1 = *(const bf16x8*)(kr + gq1);
            f32x4 sv = {};
            sv = __builtin_amdgcn_mfma_f32_16x16x32_bf16(kf0, qf0, sv, 0, 0, 0);
            sv = __builtin_amdgcn_mfma_f32_16x16x32_bf16(kf1, qf1, sv, 0, 0, 0);
            s[sub] = sv;
        }
        __builtin_amdgcn_s_setprio(0);

        // fixed-max softmax: p = exp2(s); lane covers keys k0..k0+3 at q=qbase+l15
        const int kb = c * 64;
        if (c == nch - 1) {
            const int qg = qbase + l15;
#pragma unroll
            for (int sub = 0; sub < 4; sub++) {
                const int k0 = kb + sub * 16 + quad * 4;
                unsigned short pk[4];
#pragma unroll
                for (int r = 0; r < 4; r++) {
                    float p = (k0 + r > qg) ? 0.f : exp2f(s[sub][r]);
                    lsum += p;
                    pk[r] = f2bf(p);
                }
                unsigned short* wp = (sub == 0) ? pws0 : (sub == 1) ? pws1 : (sub == 2) ? pws2 : pws3;
                *(uint2*)wp = *(uint2*)pk;
            }
        } else {
#pragma unroll
            for (int sub = 0; sub < 4; sub++) {
                unsigned short pk[4];
#pragma unroll
                for (int r = 0; r < 4; r++) {
                    float p = exp2f(s[sub][r]);
                    lsum += p;
                    pk[r] = f2bf(p);
                }
                unsigned short* wp = (sub == 0) ? pws0 : (sub == 1) ? pws1 : (sub == 2) ? pws2 : pws3;
                *(uint2*)wp = *(uint2*)pk;
            }
        }
        // wave-private write -> fragment read (same wave, cross-lane): drain DS
        asm volatile("s_waitcnt lgkmcnt(0)" ::: "memory");
        bf16x8 pf0 = *(const bf16x8*)(Pw + l15 * 64 + gq0);
        bf16x8 pf1 = *(const bf16x8*)(Pw + l15 * 64 + gq1);
        __builtin_amdgcn_s_setprio(1);
#pragma unroll
        for (int dt = 0; dt < 4; dt++) {
            const unsigned short* vrp = Vs + (dt * 16 + l15) * 64;
            bf16x8 vf0 = *(const bf16x8*)(vrp + gq0);
            bf16x8 vf1 = *(const bf16x8*)(vrp + gq1);
            // swapped: A=V (m=d), B=P (n=q)
            o[dt] = __builtin_amdgcn_mfma_f32_16x16x32_bf16(vf0, pf0, o[dt], 0, 0, 0);
            o[dt] = __builtin_amdgcn_mfma_f32_16x16x32_bf16(vf1, pf1, o[dt], 0, 0, 0);
        }
        __builtin_amdgcn_s_setprio(0);
    }

    // row sum for q = l15: reduce across the 4 quad-groups (lanes l15+16k)
    float v = lsum;
    v += __shfl_xor(v, 16);
    v += __shfl_xor(v, 32);
    const float inv = 1.0f / v;

    const int b = bh >> 4, h = bh & 15;
    const int q = qbase + l15;
    unsigned short* zrow = zb + (size_t)(b * 2048 + q) * 1024 + h * 64 + quad * 4;
#pragma unroll
    for (int dt = 0; dt < 4; dt++) {
        unsigned short pk[4];
#pragma unroll
        for (int r = 0; r < 4; r++) pk[r] = f2bf(o[dt][r] * inv);
        *(uint2*)(zrow + dt * 16) = *(uint2*)pk;
    }
}

// ---------------- launch ----------------

extern "C" void kernel_launch(void* const* d_in, const int* in_sizes, int n_in,
                              void* d_out, int out_size, void* d_ws, size_t ws_size,
                              hipStream_t stream) {
    const float* x  = (const float*)d_in[0];
    const float* WQ = (const float*)d_in[1];
    const float* WK = (const float*)d_in[2];
    const float* WV = (const float*)d_in[3];
    const float* WO = (const float*)d_in[4];
    const float* bQ = (const float*)d_in[5];
    const float* bK = (const float*)d_in[6];
    const float* bV = (const float*)d_in[7];
    const float* bO = (const float*)d_in[8];
    float* out = (float*)d_out;

    char* ws = (char*)d_ws;
    unsigned short* xb   = (unsigned short*)ws;                   // 16 MB (reused as zbuf)
    unsigned short* wqkv = (unsigned short*)(ws + (16u << 20));   // 6 MB
    unsigned short* woT  = (unsigned short*)(ws + (22u << 20));   // 2 MB
    unsigned short* qws  = (unsigned short*)(ws + (24u << 20));   // 16 MB
    unsigned short* kws  = (unsigned short*)(ws + (40u << 20));   // 16 MB
    unsigned short* vtw  = (unsigned short*)(ws + (56u << 20));   // 16 MB, [bh][64][2048]
    unsigned short* zbuf = xb;                                    // x dead after gemm_qkv

    pack_all<<<9216, 256, 0, stream>>>(x, WQ, WK, WV, WO, xb, wqkv, woT);
    gemm_qkv<<<dim3(24, 64), 256, 0, stream>>>(xb, wqkv, bQ, bK, bV, qws, kws, vtw);
    attn3<<<2048, 256, 0, stream>>>(qws, kws, vtw, zbuf);
    gemm_out<<<dim3(8, 64), 256, 0, stream>>>(zbuf, woT, bO, out);
}

// Round 10
// 254.674 us; speedup vs baseline: 1.1775x; 1.0471x over previous
//
#include <hip/hip_runtime.h>
#include <hip/hip_bf16.h>
#include <math.h>

typedef __bf16 bf16_t;
typedef bf16_t bf16x8 __attribute__((ext_vector_type(8)));
typedef float f32x4 __attribute__((ext_vector_type(4)));

#define BB 4
#define SS 2048
#define HH 16
#define DMODEL 1024
#define DHEAD 64

// Q is pre-scaled by 1/sqrt(64) * log2(e) so attention probs are exp2(q.k)
#define QSCALE 0.18033688011112042f

__device__ inline unsigned short f2bf(float f) {
    union { __hip_bfloat16 h; unsigned short u; } cvt;
    cvt.h = __float2bfloat16(f);
    return cvt.u;
}

// async global->LDS, 16B per lane. LDS dest = wave-uniform base + lane*16.
__device__ __forceinline__ void gll16(const unsigned short* g, unsigned short* l) {
    __builtin_amdgcn_global_load_lds(
        (const __attribute__((address_space(1))) unsigned int*)(g),
        (__attribute__((address_space(3))) unsigned int*)(l), 16, 0, 0);
}

// ---------------- fused pack kernel (r8-measured) ----------------

__global__ void pack_all(const float* __restrict__ x,
                         const float* __restrict__ wq, const float* __restrict__ wk,
                         const float* __restrict__ wv, const float* __restrict__ wo,
                         unsigned short* __restrict__ xb, unsigned short* __restrict__ wqkv,
                         unsigned short* __restrict__ woT) {
    __shared__ float tile[64][65];
    const int t = threadIdx.x;
    const int bid = blockIdx.x;
    if (bid < 8192) {
        int i = bid * 256 + t;
        const float4 v = ((const float4*)x)[i];
        unsigned short o[4] = { f2bf(v.x), f2bf(v.y), f2bf(v.z), f2bf(v.w) };
        *(uint2*)(xb + 4 * (size_t)i) = *(uint2*)o;
        return;
    }
    // transpose tiles: src rows m (64), cols d (64) -> dst rows d, cols m
    const float* sbase;
    int sstride;
    unsigned short* dbase;   // element (d, m) -> dbase + d*1024 + m
    if (bid < 8192 + 768) {
        int b2 = bid - 8192;
        int mat = b2 >> 8, rem = b2 & 255;
        int h = rem >> 4, mt = rem & 15;
        const float* wsrc = (mat == 0) ? wq : (mat == 1) ? wk : wv;
        sbase = wsrc + (h << 16) + ((mt * 64) << 6);
        sstride = 64;
        dbase = wqkv + (size_t)(mat * 1024 + h * 64) * 1024 + mt * 64;
    } else {
        int b3 = bid - 8960;
        int kt = b3 >> 4, nt = b3 & 15;
        sbase = wo + (size_t)(kt * 64) * 1024 + nt * 64;
        sstride = 1024;
        dbase = woT + (size_t)(nt * 64) * 1024 + kt * 64;
    }
    const int rr = t >> 4;           // 0..15
    const int c4 = (t & 15) * 4;     // 0..60
#pragma unroll
    for (int i = 0; i < 4; i++) {
        const int m = rr + 16 * i;
        const float4 v = *(const float4*)(sbase + (size_t)m * sstride + c4);
        tile[m][c4 + 0] = v.x;
        tile[m][c4 + 1] = v.y;
        tile[m][c4 + 2] = v.z;
        tile[m][c4 + 3] = v.w;
    }
    __syncthreads();
#pragma unroll
    for (int i = 0; i < 4; i++) {
        const int d = rr + 16 * i;
        unsigned short pk[4];
#pragma unroll
        for (int j = 0; j < 4; j++) pk[j] = f2bf(tile[c4 + j][d]);
        *(uint2*)(dbase + (size_t)d * 1024 + c4) = *(uint2*)pk;
    }
}

// ---------------- GEMM 1: 2-phase 128x128, BK=64, swizzled staging (r9-measured) ----------------

__global__ __launch_bounds__(256) void gemm_qkv(
    const unsigned short* __restrict__ xb,    // [8192][1024]
    const unsigned short* __restrict__ wT,    // [3072][1024]
    const float* __restrict__ bq, const float* __restrict__ bk, const float* __restrict__ bv,
    unsigned short* __restrict__ qws, unsigned short* __restrict__ kws,
    unsigned short* __restrict__ vtw)         // [64][64][2048]
{
    __shared__ __align__(16) unsigned short lA[128 * 64];   // 16 KiB
    __shared__ __align__(16) unsigned short lB[128 * 64];   // 16 KiB
    const int t = threadIdx.x;
    const int lane = t & 63;
    const int w = t >> 6;
    const int quad = lane >> 4;
    const int l15 = lane & 15;
    const int lo = l15 & 7;
    const int n0 = blockIdx.x * 128;
    const int m0 = blockIdx.y * 128;
    const int wm = (w >> 1) * 64;
    const int wn = (w & 1) * 64;
    const int mat = n0 >> 10;                 // uniform per block (1024 % 128 == 0)

    f32x4 acc[4][4] = {};

    const int sr8 = lane >> 3;                // 0..7
    const int g8 = lane & 7;                  // 0..7
    const size_t soff = (size_t)(w * 8 + sr8) * 1024 + (size_t)(((g8 ^ sr8)) << 3);
    const unsigned short* Ab = xb + (size_t)m0 * 1024 + soff;
    const unsigned short* Bb = wT + (size_t)n0 * 1024 + soff;
    unsigned short* lAw = lA + (w * 8) * 64;
    unsigned short* lBw = lB + (w * 8) * 64;

    const int c0 = ((quad ^ lo)) << 3;
    const int c1 = (((4 | quad) ^ lo)) << 3;

    if (mat != 2) {
        // swapped operands: D[m=weight n][n=x row s]
        for (int kt = 0; kt < 1024; kt += 64) {
            __syncthreads();
            gll16(Ab + kt,               lAw);
            gll16(Ab + 32 * 1024 + kt,   lAw + 32 * 64);
            gll16(Ab + 64 * 1024 + kt,   lAw + 64 * 64);
            gll16(Ab + 96 * 1024 + kt,   lAw + 96 * 64);
            gll16(Bb + kt,               lBw);
            gll16(Bb + 32 * 1024 + kt,   lBw + 32 * 64);
            gll16(Bb + 64 * 1024 + kt,   lBw + 64 * 64);
            gll16(Bb + 96 * 1024 + kt,   lBw + 96 * 64);
            __syncthreads();
            bf16x8 af[4][2], bfr[4][2];
#pragma unroll
            for (int i = 0; i < 4; i++) {
                af[i][0]  = *(const bf16x8*)(lA + (wm + i * 16 + l15) * 64 + c0);
                af[i][1]  = *(const bf16x8*)(lA + (wm + i * 16 + l15) * 64 + c1);
                bfr[i][0] = *(const bf16x8*)(lB + (wn + i * 16 + l15) * 64 + c0);
                bfr[i][1] = *(const bf16x8*)(lB + (wn + i * 16 + l15) * 64 + c1);
            }
#pragma unroll
            for (int i = 0; i < 4; i++)
#pragma unroll
                for (int j = 0; j < 4; j++) {
                    acc[i][j] = __builtin_amdgcn_mfma_f32_16x16x32_bf16(bfr[j][0], af[i][0], acc[i][j], 0, 0, 0);
                    acc[i][j] = __builtin_amdgcn_mfma_f32_16x16x32_bf16(bfr[j][1], af[i][1], acc[i][j], 0, 0, 0);
                }
        }
        // epilogue: lane holds 4 consecutive d at fixed s -> uint2 stores
        const int b = m0 >> 11;
        const float* bias_p = (mat == 0) ? bq : bk;
        const float scale = (mat == 0) ? QSCALE : 1.0f;   // fold softmax scale+log2e into Q
        unsigned short* dst = (mat == 0) ? qws : kws;
#pragma unroll
        for (int j = 0; j < 4; j++) {
            const int noff = wn + j * 16 + quad * 4;          // 0..124
            const int h = noff >> 6;
            const int hglob = ((n0 & 1023) >> 6) + h;
            const int dbase = noff & 63;
            const float4 bv4 = *(const float4*)(bias_p + hglob * 64 + dbase);
            const float bias_r[4] = { bv4.x, bv4.y, bv4.z, bv4.w };
#pragma unroll
            for (int i = 0; i < 4; i++) {
                const int s = (m0 & 2047) + wm + i * 16 + l15;
                unsigned short pk[4];
#pragma unroll
                for (int r = 0; r < 4; r++) pk[r] = f2bf((acc[i][j][r] + bias_r[r]) * scale);
                *(uint2*)(dst + (size_t)((b * 16 + hglob) * 2048 + s) * 64 + dbase) = *(uint2*)pk;
            }
        }
    } else {
        // normal order: D[m=x row s][n=weight] -> 4 consecutive s at fixed d -> uint2 into V^T
        for (int kt = 0; kt < 1024; kt += 64) {
            __syncthreads();
            gll16(Ab + kt,               lAw);
            gll16(Ab + 32 * 1024 + kt,   lAw + 32 * 64);
            gll16(Ab + 64 * 1024 + kt,   lAw + 64 * 64);
            gll16(Ab + 96 * 1024 + kt,   lAw + 96 * 64);
            gll16(Bb + kt,               lBw);
            gll16(Bb + 32 * 1024 + kt,   lBw + 32 * 64);
            gll16(Bb + 64 * 1024 + kt,   lBw + 64 * 64);
            gll16(Bb + 96 * 1024 + kt,   lBw + 96 * 64);
            __syncthreads();
            bf16x8 af[4][2], bfr[4][2];
#pragma unroll
            for (int i = 0; i < 4; i++) {
                af[i][0]  = *(const bf16x8*)(lA + (wm + i * 16 + l15) * 64 + c0);
                af[i][1]  = *(const bf16x8*)(lA + (wm + i * 16 + l15) * 64 + c1);
                bfr[i][0] = *(const bf16x8*)(lB + (wn + i * 16 + l15) * 64 + c0);
                bfr[i][1] = *(const bf16x8*)(lB + (wn + i * 16 + l15) * 64 + c1);
            }
#pragma unroll
            for (int i = 0; i < 4; i++)
#pragma unroll
                for (int j = 0; j < 4; j++) {
                    acc[i][j] = __builtin_amdgcn_mfma_f32_16x16x32_bf16(af[i][0], bfr[j][0], acc[i][j], 0, 0, 0);
                    acc[i][j] = __builtin_amdgcn_mfma_f32_16x16x32_bf16(af[i][1], bfr[j][1], acc[i][j], 0, 0, 0);
                }
        }
        const int b = m0 >> 11;
#pragma unroll
        for (int j = 0; j < 4; j++) {
            const int n1 = (n0 & 1023) + wn + j * 16 + l15;
            const int h = n1 >> 6, d = n1 & 63;
            const float bias = bv[h * 64 + d];
#pragma unroll
            for (int i = 0; i < 4; i++) {
                const int s0 = (m0 & 2047) + wm + i * 16 + quad * 4;
                unsigned short pk[4];
#pragma unroll
                for (int r = 0; r < 4; r++) pk[r] = f2bf(acc[i][j][r] + bias);
                *(uint2*)(vtw + ((size_t)(b * 16 + h) * 64 + d) * 2048 + s0) = *(uint2*)pk;
            }
        }
    }
}

// ---------------- GEMM 2: 2-phase 128x128, BK=64, swizzled (r9-measured) ----------------

__global__ __launch_bounds__(256) void gemm_out(
    const unsigned short* __restrict__ zb,    // [8192][1024]
    const unsigned short* __restrict__ wT,    // [1024][1024]
    const float* __restrict__ bo,
    float* __restrict__ out)
{
    __shared__ __align__(16) unsigned short lA[128 * 64];
    __shared__ __align__(16) unsigned short lB[128 * 64];
    const int t = threadIdx.x;
    const int lane = t & 63;
    const int w = t >> 6;
    const int quad = lane >> 4;
    const int l15 = lane & 15;
    const int lo = l15 & 7;
    const int n0 = blockIdx.x * 128;
    const int m0 = blockIdx.y * 128;
    const int wm = (w >> 1) * 64;
    const int wn = (w & 1) * 64;

    f32x4 acc[4][4] = {};

    const int sr8 = lane >> 3;
    const int g8 = lane & 7;
    const size_t soff = (size_t)(w * 8 + sr8) * 1024 + (size_t)(((g8 ^ sr8)) << 3);
    const unsigned short* Ab = zb + (size_t)m0 * 1024 + soff;
    const unsigned short* Bb = wT + (size_t)n0 * 1024 + soff;
    unsigned short* lAw = lA + (w * 8) * 64;
    unsigned short* lBw = lB + (w * 8) * 64;

    const int c0 = ((quad ^ lo)) << 3;
    const int c1 = (((4 | quad) ^ lo)) << 3;

    for (int kt = 0; kt < 1024; kt += 64) {
        __syncthreads();
        gll16(Ab + kt,               lAw);
        gll16(Ab + 32 * 1024 + kt,   lAw + 32 * 64);
        gll16(Ab + 64 * 1024 + kt,   lAw + 64 * 64);
        gll16(Ab + 96 * 1024 + kt,   lAw + 96 * 64);
        gll16(Bb + kt,               lBw);
        gll16(Bb + 32 * 1024 + kt,   lBw + 32 * 64);
        gll16(Bb + 64 * 1024 + kt,   lBw + 64 * 64);
        gll16(Bb + 96 * 1024 + kt,   lBw + 96 * 64);
        __syncthreads();
        bf16x8 af[4][2], bfr[4][2];
#pragma unroll
        for (int i = 0; i < 4; i++) {
            af[i][0]  = *(const bf16x8*)(lA + (wm + i * 16 + l15) * 64 + c0);
            af[i][1]  = *(const bf16x8*)(lA + (wm + i * 16 + l15) * 64 + c1);
            bfr[i][0] = *(const bf16x8*)(lB + (wn + i * 16 + l15) * 64 + c0);
            bfr[i][1] = *(const bf16x8*)(lB + (wn + i * 16 + l15) * 64 + c1);
        }
#pragma unroll
        for (int i = 0; i < 4; i++)
#pragma unroll
            for (int j = 0; j < 4; j++) {
                acc[i][j] = __builtin_amdgcn_mfma_f32_16x16x32_bf16(bfr[j][0], af[i][0], acc[i][j], 0, 0, 0);
                acc[i][j] = __builtin_amdgcn_mfma_f32_16x16x32_bf16(bfr[j][1], af[i][1], acc[i][j], 0, 0, 0);
            }
    }

    // swapped D: lane holds 4 consecutive n at fixed s -> float4 stores
#pragma unroll
    for (int j = 0; j < 4; j++) {
        const int nbase = n0 + wn + j * 16 + quad * 4;
        const float4 bv4 = *(const float4*)(bo + nbase);
#pragma unroll
        for (int i = 0; i < 4; i++) {
            const int s = m0 + wm + i * 16 + l15;
            float4 v;
            v.x = acc[i][j][0] + bv4.x;
            v.y = acc[i][j][1] + bv4.y;
            v.z = acc[i][j][2] + bv4.z;
            v.w = acc[i][j][3] + bv4.w;
            *(float4*)(out + (size_t)s * 1024 + nbase) = v;
        }
    }
}

// ---------------- attention v8: 8-wave blocks, 128 q-rows, shared K/V chunk ----------------
// vs v6 (4-wave/64q): same single-buffered K/V chunk now feeds 8 waves -> per-CU
// chunk-events HALVE (132 -> 68, the same event-halving lever that took gemm_qkv
// 86.5 -> 72.8 via BK=64), per-thread staging halves (32B), and occupancy rises
// 24 -> 32 waves/CU (LDS 32 KiB -> 4 blocks = wave cap; v7's dbuf regression was
// the occupancy loss, so buffers stay single). Masking now per-chunk: any chunk
// with kb+63 > qbase uses the masked path; fully-masked waves skip compute but
// keep the uniform barriers.

__global__ __launch_bounds__(512) void attn3(
    const unsigned short* __restrict__ qws,
    const unsigned short* __restrict__ kws,
    const unsigned short* __restrict__ vtw,   // [bh][64][2048]
    unsigned short* __restrict__ zb)          // [8192][1024], col = h*64+d
{
    __shared__ __align__(16) unsigned short Ks[64 * 64];     //  8 KiB
    __shared__ __align__(16) unsigned short Vs[64 * 64];     //  8 KiB [d][key]
    __shared__ __align__(16) unsigned short Ps[8 * 16 * 64]; // 16 KiB, per-wave [q=16][key=64]

    const int t = threadIdx.x;
    const int lane = t & 63;
    const int w = t >> 6;            // 0..7
    const int quad = lane >> 4;
    const int l15 = lane & 15;
    const int lo = l15 & 7;

    const int qt = 15 - (blockIdx.x >> 6);   // longest blocks dispatched first
    const int bh = blockIdx.x & 63;
    const int qbase = qt * 128 + w * 16;     // wave's 16 q-rows
    const size_t base = (size_t)bh * SS * DHEAD;
    const unsigned short* Q = qws + base;
    const unsigned short* K = kws + base;
    const unsigned short* Vt = vtw + base;   // [64][2048]

    bf16x8 qf0 = *(const bf16x8*)(Q + (size_t)(qbase + l15) * 64 + quad * 8);
    bf16x8 qf1 = *(const bf16x8*)(Q + (size_t)(qbase + l15) * 64 + 32 + quad * 8);

    f32x4 o[4] = {};          // swapped PV: o[dt] rows = d (dt*16+quad*4+r), col = q (l15)
    float lsum = 0.f;         // row-sum for q = qbase + l15
    unsigned short* Pw = Ps + w * 16 * 64;

    // staging: 512 threads x (16B K + 16B V); thread t covers row sr, granule g0
    const int sr = t >> 3;           // 0..63
    const int g0 = t & 7;            // 0..7
    const int swz = ((g0 ^ (sr & 7)) << 3);
    unsigned short* ksw = Ks + sr * 64 + swz;
    unsigned short* vsw = Vs + sr * 64 + swz;
    const unsigned short* Kg = K + (size_t)sr * 64 + g0 * 8;
    const unsigned short* Vg = Vt + (size_t)sr * 2048 + g0 * 8;

    // fragment reads: original granules quad / quad+4 of row with row&7==l15&7
    const int gq0 = ((quad ^ lo) << 3);
    const int gq1 = (((quad + 4) ^ lo) << 3);

    // P write pointers (loop-invariant): row q=l15, 8B slot (sub*4+quad)^(lo<<1)
    unsigned short* pwr = Pw + l15 * 64;
    unsigned short* pws0 = pwr + (((0 + quad) ^ (lo << 1)) << 2);
    unsigned short* pws1 = pwr + (((4 + quad) ^ (lo << 1)) << 2);
    unsigned short* pws2 = pwr + (((8 + quad) ^ (lo << 1)) << 2);
    unsigned short* pws3 = pwr + (((12 + quad) ^ (lo << 1)) << 2);

    const int nch = 2 * qt + 2;

    // prologue: prefetch chunk 0 into registers
    uint4 kr = *(const uint4*)(Kg);
    uint4 vr = *(const uint4*)(Vg);

    for (int c = 0; c < nch; c++) {
        __builtin_amdgcn_sched_barrier(0);
        __builtin_amdgcn_s_barrier();          // LDS free: all waves consumed chunk c-1
        *(uint4*)ksw = kr;
        *(uint4*)vsw = vr;
        if (c + 1 < nch) {                     // issue next chunk's loads; NOT waited here
            kr = *(const uint4*)(Kg + (size_t)(c + 1) * 64 * 64);
            vr = *(const uint4*)(Vg + (size_t)(c + 1) * 64);
        }
        asm volatile("s_waitcnt lgkmcnt(0)" ::: "memory");   // my ds_writes done (vmcnt stays)
        __builtin_amdgcn_s_barrier();          // LDS ready
        __builtin_amdgcn_sched_barrier(0);

        const int kb = c * 64;
        if (kb > qbase + 15) continue;         // all keys masked for this wave: skip compute
                                               // (barriers above/below chunk are uniform)

        // scores, SWAPPED: A=K, B=Q -> D[row=key quad*4+r][col=q l15]
        f32x4 s[4];
        __builtin_amdgcn_s_setprio(1);
#pragma unroll
        for (int sub = 0; sub < 4; sub++) {
            const unsigned short* krow = Ks + (sub * 16 + l15) * 64;
            bf16x8 kf0 = *(const bf16x8*)(krow + gq0);
            bf16x8 kf1 = *(const bf16x8*)(krow + gq1);
            f32x4 sv = {};
            sv = __builtin_amdgcn_mfma_f32_16x16x32_bf16(kf0, qf0, sv, 0, 0, 0);
            sv = __builtin_amdgcn_mfma_f32_16x16x32_bf16(kf1, qf1, sv, 0, 0, 0);
            s[sub] = sv;
        }
        __builtin_amdgcn_s_setprio(0);

        // fixed-max softmax: p = exp2(s); lane covers keys k0..k0+3 at q=qbase+l15
        if (kb + 63 > qbase) {                 // some (key,q) pairs masked in this chunk
            const int qg = qbase + l15;
#pragma unroll
            for (int sub = 0; sub < 4; sub++) {
                const int k0 = kb + sub * 16 + quad * 4;
                unsigned short pk[4];
#pragma unroll
                for (int r = 0; r < 4; r++) {
                    float p = (k0 + r > qg) ? 0.f : exp2f(s[sub][r]);
                    lsum += p;
                    pk[r] = f2bf(p);
                }
                unsigned short* wp = (sub == 0) ? pws0 : (sub == 1) ? pws1 : (sub == 2) ? pws2 : pws3;
                *(uint2*)wp = *(uint2*)pk;
            }
        } else {
#pragma unroll
            for (int sub = 0; sub < 4; sub++) {
                unsigned short pk[4];
#pragma unroll
                for (int r = 0; r < 4; r++) {
                    float p = exp2f(s[sub][r]);
                    lsum += p;
                    pk[r] = f2bf(p);
                }
                unsigned short* wp = (sub == 0) ? pws0 : (sub == 1) ? pws1 : (sub == 2) ? pws2 : pws3;
                *(uint2*)wp = *(uint2*)pk;
            }
        }
        // wave-private write -> fragment read (same wave, cross-lane): drain DS
        asm volatile("s_waitcnt lgkmcnt(0)" ::: "memory");
        bf16x8 pf0 = *(const bf16x8*)(Pw + l15 * 64 + gq0);
        bf16x8 pf1 = *(const bf16x8*)(Pw + l15 * 64 + gq1);
        __builtin_amdgcn_s_setprio(1);
#pragma unroll
        for (int dt = 0; dt < 4; dt++) {
            const unsigned short* vrp = Vs + (dt * 16 + l15) * 64;
            bf16x8 vf0 = *(const bf16x8*)(vrp + gq0);
            bf16x8 vf1 = *(const bf16x8*)(vrp + gq1);
            // swapped: A=V (m=d), B=P (n=q)
            o[dt] = __builtin_amdgcn_mfma_f32_16x16x32_bf16(vf0, pf0, o[dt], 0, 0, 0);
            o[dt] = __builtin_amdgcn_mfma_f32_16x16x32_bf16(vf1, pf1, o[dt], 0, 0, 0);
        }
        __builtin_amdgcn_s_setprio(0);
    }

    // row sum for q = l15: reduce across the 4 quad-groups (lanes l15+16k)
    float v = lsum;
    v += __shfl_xor(v, 16);
    v += __shfl_xor(v, 32);
    const float inv = 1.0f / v;

    const int b = bh >> 4, h = bh & 15;
    const int q = qbase + l15;
    unsigned short* zrow = zb + (size_t)(b * 2048 + q) * 1024 + h * 64 + quad * 4;
#pragma unroll
    for (int dt = 0; dt < 4; dt++) {
        unsigned short pk[4];
#pragma unroll
        for (int r = 0; r < 4; r++) pk[r] = f2bf(o[dt][r] * inv);
        *(uint2*)(zrow + dt * 16) = *(uint2*)pk;
    }
}

// ---------------- launch ----------------

extern "C" void kernel_launch(void* const* d_in, const int* in_sizes, int n_in,
                              void* d_out, int out_size, void* d_ws, size_t ws_size,
                              hipStream_t stream) {
    const float* x  = (const float*)d_in[0];
    const float* WQ = (const float*)d_in[1];
    const float* WK = (const float*)d_in[2];
    const float* WV = (const float*)d_in[3];
    const float* WO = (const float*)d_in[4];
    const float* bQ = (const float*)d_in[5];
    const float* bK = (const float*)d_in[6];
    const float* bV = (const float*)d_in[7];
    const float* bO = (const float*)d_in[8];
    float* out = (float*)d_out;

    char* ws = (char*)d_ws;
    unsigned short* xb   = (unsigned short*)ws;                   // 16 MB (reused as zbuf)
    unsigned short* wqkv = (unsigned short*)(ws + (16u << 20));   // 6 MB
    unsigned short* woT  = (unsigned short*)(ws + (22u << 20));   // 2 MB
    unsigned short* qws  = (unsigned short*)(ws + (24u << 20));   // 16 MB
    unsigned short* kws  = (unsigned short*)(ws + (40u << 20));   // 16 MB
    unsigned short* vtw  = (unsigned short*)(ws + (56u << 20));   // 16 MB, [bh][64][2048]
    unsigned short* zbuf = xb;                                    // x dead after gemm_qkv

    pack_all<<<9216, 256, 0, stream>>>(x, WQ, WK, WV, WO, xb, wqkv, woT);
    gemm_qkv<<<dim3(24, 64), 256, 0, stream>>>(xb, wqkv, bQ, bK, bV, qws, kws, vtw);
    attn3<<<1024, 512, 0, stream>>>(qws, kws, vtw, zbuf);
    gemm_out<<<dim3(8, 64), 256, 0, stream>>>(zbuf, woT, bO, out);
}